// Round 10
// baseline (295.452 us; speedup 1.0000x reference)
//
#include <hip/hip_runtime.h>

#define TT 512
#define FF 8
#define CC 16
#define HH 10
#define G4 40

__device__ __forceinline__ float rl(float v, int k){
    return __int_as_float(__builtin_amdgcn_readlane(__float_as_int(v), k));
}
__device__ __forceinline__ float sigf(float z){
    return __builtin_amdgcn_rcpf(1.f + __expf(-z));
}
__device__ __forceinline__ float tanh_f(float z){
    return 1.f - 2.f * __builtin_amdgcn_rcpf(1.f + __expf(2.f * z));
}
#define PIN(v) asm volatile("" : "+v"(v))

// DPP quad_perm broadcast: every lane of a quad gets quad-lane Q's value. Pure
// VALU (no DS pipe, no address math) — replaces dynamic __shfl/bpermute.
template<int Q>
__device__ __forceinline__ float quadb(float v){
    return __int_as_float(__builtin_amdgcn_mov_dpp(__float_as_int(v), Q * 0x55, 0xf, 0xf, false));
}

// ===================== shared conv macro (A + fused fallback) ================
#define CONV_Y(Y) do{                                                                              \
    float a0 = cb, a1 = 0.f;                                                                       \
    a0 = fmaf(w0a.x, cw0,  a0); a1 = fmaf(w1a.x, cw1,  a1); a0 = fmaf(w2a.x, cw2,  a0);            \
    a1 = fmaf(w0a.y, cw3,  a1); a0 = fmaf(w1a.y, cw4,  a0); a1 = fmaf(w2a.y, cw5,  a1);            \
    a0 = fmaf(w0a.z, cw6,  a0); a1 = fmaf(w1a.z, cw7,  a1); a0 = fmaf(w2a.z, cw8,  a0);            \
    a1 = fmaf(w0a.w, cw9,  a1); a0 = fmaf(w1a.w, cw10, a0); a1 = fmaf(w2a.w, cw11, a1);            \
    a0 = fmaf(w0b.x, cw12, a0); a1 = fmaf(w1b.x, cw13, a1); a0 = fmaf(w2b.x, cw14, a0);            \
    a1 = fmaf(w0b.y, cw15, a1); a0 = fmaf(w1b.y, cw16, a0); a1 = fmaf(w2b.y, cw17, a1);            \
    a0 = fmaf(w0b.z, cw18, a0); a1 = fmaf(w1b.z, cw19, a1); a0 = fmaf(w2b.z, cw20, a0);            \
    a1 = fmaf(w0b.w, cw21, a1); a0 = fmaf(w1b.w, cw22, a0); a1 = fmaf(w2b.w, cw23, a1);            \
    Y = fmaxf(a0 + a1, 0.f);                                                                       \
}while(0)

// ======================= Kernel A: conv + W_ih1*y -> xg ======================
// One wave per batch. Lane groups g=lane>>4 conv 4 timesteps per iteration
// (ch = lane&15); then per sub-step s all lanes do the 16-wide xg matvec via
// readlane from group s's lanes. Lane l (<40) owns gate row r=(l&3)*10+(l>>2);
// xg stored in LANE order (B uses the same lane->row map).
__global__ __launch_bounds__(64, 1)
void conv_xg(const float* __restrict__ x,
             const float* __restrict__ conv_w, const float* __restrict__ conv_b,
             const float* __restrict__ w_ih1,  const float* __restrict__ b_ih1,
             const float* __restrict__ b_hh1,
             float* __restrict__ xg)
{
    __shared__ float wl[64][43];   // stride 43: bank=(11j+m)%32, gcd(11,32)=1 -> free
    const int lane = threadIdx.x;
    const int b    = blockIdx.x;
    const int ch   = lane & 15;
    const int g    = lane >> 4;
    const int u_c  = (lane < G4) ? (lane >> 2) : 9;
    const int q    = lane & 3;
    const int r    = q * 10 + u_c;

    {
        float* mr_ = wl[lane];
        const float* cwp = conv_w + ch*24;
        #pragma unroll
        for (int m = 0; m < 24; ++m) mr_[m] = cwp[m];
        const float* wip = w_ih1 + r*CC;
        #pragma unroll
        for (int k = 0; k < CC; ++k) mr_[24+k] = wip[k];
        mr_[40] = b_ih1[r] + b_hh1[r];
        mr_[41] = conv_b[ch];
    }
    __syncthreads();
    const float* mr = wl[lane];

    float cw0=mr[0],  cw1=mr[1],  cw2=mr[2],  cw3=mr[3],  cw4=mr[4],  cw5=mr[5];
    float cw6=mr[6],  cw7=mr[7],  cw8=mr[8],  cw9=mr[9],  cw10=mr[10],cw11=mr[11];
    float cw12=mr[12],cw13=mr[13],cw14=mr[14],cw15=mr[15],cw16=mr[16],cw17=mr[17];
    float cw18=mr[18],cw19=mr[19],cw20=mr[20],cw21=mr[21],cw22=mr[22],cw23=mr[23];
    PIN(cw0);PIN(cw1);PIN(cw2);PIN(cw3);PIN(cw4);PIN(cw5);PIN(cw6);PIN(cw7);
    PIN(cw8);PIN(cw9);PIN(cw10);PIN(cw11);PIN(cw12);PIN(cw13);PIN(cw14);PIN(cw15);
    PIN(cw16);PIN(cw17);PIN(cw18);PIN(cw19);PIN(cw20);PIN(cw21);PIN(cw22);PIN(cw23);
    float wi0=mr[24], wi1=mr[25], wi2=mr[26], wi3=mr[27];
    float wi4=mr[28], wi5=mr[29], wi6=mr[30], wi7=mr[31];
    float wi8=mr[32], wi9=mr[33], wi10=mr[34],wi11=mr[35];
    float wi12=mr[36],wi13=mr[37],wi14=mr[38],wi15=mr[39];
    PIN(wi0);PIN(wi1);PIN(wi2);PIN(wi3);PIN(wi4);PIN(wi5);PIN(wi6);PIN(wi7);
    PIN(wi8);PIN(wi9);PIN(wi10);PIN(wi11);PIN(wi12);PIN(wi13);PIN(wi14);PIN(wi15);
    float b1r = mr[40]; PIN(b1r);
    float cb  = mr[41]; PIN(cb);

    const float* xb  = x  + (size_t)b * (TT*FF);
    float*       xgb = xg + (size_t)b * (TT*G4);
    const float4 z4 = make_float4(0.f,0.f,0.f,0.f);

    #pragma unroll 1
    for (int tb = 0; tb < TT/4; ++tb){
        const int tq = tb*4 + g;          // this group's conv timestep
        float4 w0a, w0b, w1a, w1b, w2a, w2b;
        if (tq == 0){ w0a = z4; w0b = z4; }
        else { const float* p = xb + (tq-1)*FF; w0a = *(const float4*)p; w0b = *(const float4*)(p+4); }
        { const float* p = xb + tq*FF; w1a = *(const float4*)p; w1b = *(const float4*)(p+4); }
        if (tq + 1 < TT){ const float* p = xb + (tq+1)*FF; w2a = *(const float4*)p; w2b = *(const float4*)(p+4); }
        else { w2a = z4; w2b = z4; }

        float y; CONV_Y(y);               // y for timestep tb*4+g, channel ch

        #pragma unroll
        for (int s = 0; s < 4; ++s){
            float e0 = b1r, e1 = 0.f;
            e0 = fmaf(rl(y, s*16+0),  wi0,  e0);  e1 = fmaf(rl(y, s*16+1),  wi1,  e1);
            e0 = fmaf(rl(y, s*16+2),  wi2,  e0);  e1 = fmaf(rl(y, s*16+3),  wi3,  e1);
            e0 = fmaf(rl(y, s*16+4),  wi4,  e0);  e1 = fmaf(rl(y, s*16+5),  wi5,  e1);
            e0 = fmaf(rl(y, s*16+6),  wi6,  e0);  e1 = fmaf(rl(y, s*16+7),  wi7,  e1);
            e0 = fmaf(rl(y, s*16+8),  wi8,  e0);  e1 = fmaf(rl(y, s*16+9),  wi9,  e1);
            e0 = fmaf(rl(y, s*16+10), wi10, e0);  e1 = fmaf(rl(y, s*16+11), wi11, e1);
            e0 = fmaf(rl(y, s*16+12), wi12, e0);  e1 = fmaf(rl(y, s*16+13), wi13, e1);
            e0 = fmaf(rl(y, s*16+14), wi14, e0);  e1 = fmaf(rl(y, s*16+15), wi15, e1);
            if (lane < G4) xgb[(tb*4+s)*G4 + lane] = e0 + e1;   // 160B coalesced
        }
    }
}

// ======================= Kernel B: pure 2-layer recurrence ===================
// Unit-major quad layout: lane = 4*u + q (u<10), q: 0=i,1=f,2=g,3=o.
// Gate collect = 4 DPP quad broadcasts (no DS). h broadcasts = readlane(4k).
#define BH1B                                                                     \
    const float hs0=rl(h1,0),  hs1=rl(h1,4),  hs2=rl(h1,8),  hs3=rl(h1,12),      \
                hs4=rl(h1,16), hs5=rl(h1,20), hs6=rl(h1,24), hs7=rl(h1,28),      \
                hs8=rl(h1,32), hs9=rl(h1,36);

#define BL2 do{                                                                  \
    float d0 = b2, d1 = 0.f;                                                     \
    d0 = fmaf(hs0, wi2_0, d0);  d1 = fmaf(hs1, wi2_1, d1);                       \
    d0 = fmaf(hs2, wi2_2, d0);  d1 = fmaf(hs3, wi2_3, d1);                       \
    d0 = fmaf(hs4, wi2_4, d0);  d1 = fmaf(hs5, wi2_5, d1);                       \
    d0 = fmaf(hs6, wi2_6, d0);  d1 = fmaf(hs7, wi2_7, d1);                       \
    d0 = fmaf(hs8, wi2_8, d0);  d1 = fmaf(hs9, wi2_9, d1);                       \
    d0 = fmaf(rl(h2,0),  wh2_0, d0);  d1 = fmaf(rl(h2,4),  wh2_1, d1);           \
    d0 = fmaf(rl(h2,8),  wh2_2, d0);  d1 = fmaf(rl(h2,12), wh2_3, d1);           \
    d0 = fmaf(rl(h2,16), wh2_4, d0);  d1 = fmaf(rl(h2,20), wh2_5, d1);           \
    d0 = fmaf(rl(h2,24), wh2_6, d0);  d1 = fmaf(rl(h2,28), wh2_7, d1);           \
    d0 = fmaf(rl(h2,32), wh2_8, d0);  d1 = fmaf(rl(h2,36), wh2_9, d1);           \
    const float g2  = d0 + d1;                                                   \
    const float sg2 = sigf(g2 * zM);                                             \
    const float act2 = fmaf(aA, sg2, aB);                                        \
    const float ai2 = quadb<0>(act2);                                            \
    const float af2 = quadb<1>(act2);                                            \
    const float ag2 = quadb<2>(act2);                                            \
    const float ao2 = quadb<3>(act2);                                            \
    c2 = fmaf(af2, c2, ai2 * ag2);                                               \
    h2 = ao2 * tanh_f(c2);                                                       \
}while(0)

#define BL1(XGV) do{                                                             \
    float e0 = (XGV), e1 = 0.f;                                                  \
    e0 = fmaf(hs0, wh1_0, e0);  e1 = fmaf(hs1, wh1_1, e1);                       \
    e0 = fmaf(hs2, wh1_2, e0);  e1 = fmaf(hs3, wh1_3, e1);                       \
    e0 = fmaf(hs4, wh1_4, e0);  e1 = fmaf(hs5, wh1_5, e1);                       \
    e0 = fmaf(hs6, wh1_6, e0);  e1 = fmaf(hs7, wh1_7, e1);                       \
    e0 = fmaf(hs8, wh1_8, e0);  e1 = fmaf(hs9, wh1_9, e1);                       \
    const float g1  = e0 + e1;                                                   \
    const float sg1 = sigf(g1 * zM);                                             \
    const float act1 = fmaf(aA, sg1, aB);                                        \
    const float ai1 = quadb<0>(act1);                                            \
    const float af1 = quadb<1>(act1);                                            \
    const float ag1 = quadb<2>(act1);                                            \
    const float ao1 = quadb<3>(act1);                                            \
    c1 = fmaf(af1, c1, ai1 * ag1);                                               \
    h1n = ao1 * tanh_f(c1);                                                      \
}while(0)

__global__ __launch_bounds__(64, 1)
void lstm_seq(const float* __restrict__ xg,
              const float* __restrict__ w_hh1,
              const float* __restrict__ w_ih2,  const float* __restrict__ w_hh2,
              const float* __restrict__ b_ih2,  const float* __restrict__ b_hh2,
              const float* __restrict__ lin_w,  const float* __restrict__ lin_b,
              float* __restrict__ out)
{
    __shared__ float wl[64][31];   // stride 31: bank=(31j+m)%32=(m-j)%32 -> conflict-free
    const int lane  = threadIdx.x;
    const int batch = blockIdx.x;
    const int u_c   = (lane < G4) ? (lane >> 2) : 9;
    const int q     = lane & 3;
    const int r     = q * 10 + u_c;
    const bool isG  = (q == 2);
    float zM = isG ? 2.f : 1.f;    // tanh(z) = 2*sig(2z)-1
    float aA = isG ? 2.f : 1.f;
    float aB = isG ? -1.f : 0.f;
    PIN(zM); PIN(aA); PIN(aB);

    {
        float* mr_ = wl[lane];
        const float* q1 = w_hh1 + r*HH;
        const float* q2 = w_ih2 + r*HH;
        const float* q3 = w_hh2 + r*HH;
        #pragma unroll
        for (int m = 0; m < HH; ++m){ mr_[m]=q1[m]; mr_[10+m]=q2[m]; mr_[20+m]=q3[m]; }
        mr_[30] = b_ih2[r] + b_hh2[r];
    }
    __syncthreads();
    const float* mr = wl[lane];

    float wh1_0=mr[0], wh1_1=mr[1], wh1_2=mr[2], wh1_3=mr[3], wh1_4=mr[4];
    float wh1_5=mr[5], wh1_6=mr[6], wh1_7=mr[7], wh1_8=mr[8], wh1_9=mr[9];
    PIN(wh1_0);PIN(wh1_1);PIN(wh1_2);PIN(wh1_3);PIN(wh1_4);
    PIN(wh1_5);PIN(wh1_6);PIN(wh1_7);PIN(wh1_8);PIN(wh1_9);
    float wi2_0=mr[10],wi2_1=mr[11],wi2_2=mr[12],wi2_3=mr[13],wi2_4=mr[14];
    float wi2_5=mr[15],wi2_6=mr[16],wi2_7=mr[17],wi2_8=mr[18],wi2_9=mr[19];
    PIN(wi2_0);PIN(wi2_1);PIN(wi2_2);PIN(wi2_3);PIN(wi2_4);
    PIN(wi2_5);PIN(wi2_6);PIN(wi2_7);PIN(wi2_8);PIN(wi2_9);
    float wh2_0=mr[20],wh2_1=mr[21],wh2_2=mr[22],wh2_3=mr[23],wh2_4=mr[24];
    float wh2_5=mr[25],wh2_6=mr[26],wh2_7=mr[27],wh2_8=mr[28],wh2_9=mr[29];
    PIN(wh2_0);PIN(wh2_1);PIN(wh2_2);PIN(wh2_3);PIN(wh2_4);
    PIN(wh2_5);PIN(wh2_6);PIN(wh2_7);PIN(wh2_8);PIN(wh2_9);
    float b2 = mr[30]; PIN(b2);

    const float* xp = xg + (size_t)batch * (TT*G4) + ((lane < G4) ? lane : (G4-1));

    float h1 = 0.f, c1 = 0.f, h2 = 0.f, c2 = 0.f, h1n;

    float xgv = xp[0];
    {   // t=0: layer1 only (h1(-1)=0)
        BH1B;
        BL1(xgv);
        h1 = h1n;
    }
    float xgn = xp[G4];

    #pragma unroll 2
    for (int t = 1; t < TT; ++t){
        const float xgc = xgn;
        const int tn = (t + 1 < TT) ? (t + 1) : (TT - 1);
        xgn = xp[(size_t)tn * G4];         // prefetch next step (L3-resident)
        BH1B;                              // h1(t-1) broadcasts, shared
        BL2;                               // h2(t-1)  — chain A
        BL1(xgc);                          // h1(t)    — chain B
        h1 = h1n;
    }
    { BH1B; BL2; }                         // t = TT-1

    // out = sigmoid(h2 . lin_w + lin_b); h2[u] lives in lanes 4u (q==0)
    float part = (q == 0 && lane < G4) ? h2 * lin_w[u_c] : 0.f;
    part += __shfl_xor(part, 4,  64);
    part += __shfl_xor(part, 8,  64);
    part += __shfl_xor(part, 16, 64);
    part += __shfl_xor(part, 32, 64);
    if (lane == 0) out[batch] = sigf(part + lin_b[0]);
}

// ======================= fused fallback (R9, passed) =========================
#define H1BCAST                                                                                    \
    const float hs0=rl(h1,0), hs1=rl(h1,1), hs2=rl(h1,2), hs3=rl(h1,3), hs4=rl(h1,4),              \
                hs5=rl(h1,5), hs6=rl(h1,6), hs7=rl(h1,7), hs8=rl(h1,8), hs9=rl(h1,9);

#define LAYER2 do{                                                                                 \
    float d0 = b2, d1 = 0.f;                                                                       \
    d0 = fmaf(hs0, wi2_0, d0);  d1 = fmaf(hs1, wi2_1, d1);                                         \
    d0 = fmaf(hs2, wi2_2, d0);  d1 = fmaf(hs3, wi2_3, d1);                                         \
    d0 = fmaf(hs4, wi2_4, d0);  d1 = fmaf(hs5, wi2_5, d1);                                         \
    d0 = fmaf(hs6, wi2_6, d0);  d1 = fmaf(hs7, wi2_7, d1);                                         \
    d0 = fmaf(hs8, wi2_8, d0);  d1 = fmaf(hs9, wi2_9, d1);                                         \
    d0 = fmaf(rl(h2,0), wh2_0, d0);  d1 = fmaf(rl(h2,1), wh2_1, d1);                               \
    d0 = fmaf(rl(h2,2), wh2_2, d0);  d1 = fmaf(rl(h2,3), wh2_3, d1);                               \
    d0 = fmaf(rl(h2,4), wh2_4, d0);  d1 = fmaf(rl(h2,5), wh2_5, d1);                               \
    d0 = fmaf(rl(h2,6), wh2_6, d0);  d1 = fmaf(rl(h2,7), wh2_7, d1);                               \
    d0 = fmaf(rl(h2,8), wh2_8, d0);  d1 = fmaf(rl(h2,9), wh2_9, d1);                               \
    const float g2  = d0 + d1;                                                                     \
    const float sg2 = sigf(g2 * zM);                                                               \
    const float act2 = fmaf(aA, sg2, aB);                                                          \
    const float ai2 = __shfl(act2, u,      64);                                                    \
    const float af2 = __shfl(act2, u + 10, 64);                                                    \
    const float ag2 = __shfl(act2, u + 20, 64);                                                    \
    const float ao2 = __shfl(act2, u + 30, 64);                                                    \
    c2 = fmaf(af2, c2, ai2 * ag2);                                                                 \
    h2 = ao2 * tanh_f(c2);                                                                         \
}while(0)

#define LAYER1(YV) do{                                                                             \
    float e0 = b1, e1 = 0.f;                                                                       \
    e0 = fmaf(rl(YV,0),  wi0,  e0);  e1 = fmaf(rl(YV,1),  wi1,  e1);                               \
    e0 = fmaf(rl(YV,2),  wi2,  e0);  e1 = fmaf(rl(YV,3),  wi3,  e1);                               \
    e0 = fmaf(rl(YV,4),  wi4,  e0);  e1 = fmaf(rl(YV,5),  wi5,  e1);                               \
    e0 = fmaf(rl(YV,6),  wi6,  e0);  e1 = fmaf(rl(YV,7),  wi7,  e1);                               \
    e0 = fmaf(rl(YV,8),  wi8,  e0);  e1 = fmaf(rl(YV,9),  wi9,  e1);                               \
    e0 = fmaf(rl(YV,10), wi10, e0);  e1 = fmaf(rl(YV,11), wi11, e1);                               \
    e0 = fmaf(rl(YV,12), wi12, e0);  e1 = fmaf(rl(YV,13), wi13, e1);                               \
    e0 = fmaf(rl(YV,14), wi14, e0);  e1 = fmaf(rl(YV,15), wi15, e1);                               \
    e0 = fmaf(hs0, wh1_0, e0);  e1 = fmaf(hs1, wh1_1, e1);                                         \
    e0 = fmaf(hs2, wh1_2, e0);  e1 = fmaf(hs3, wh1_3, e1);                                         \
    e0 = fmaf(hs4, wh1_4, e0);  e1 = fmaf(hs5, wh1_5, e1);                                         \
    e0 = fmaf(hs6, wh1_6, e0);  e1 = fmaf(hs7, wh1_7, e1);                                         \
    e0 = fmaf(hs8, wh1_8, e0);  e1 = fmaf(hs9, wh1_9, e1);                                         \
    const float g1  = e0 + e1;                                                                     \
    const float sg1 = sigf(g1 * zM);                                                               \
    const float act1 = fmaf(aA, sg1, aB);                                                          \
    const float ai1 = __shfl(act1, u,      64);                                                    \
    const float af1 = __shfl(act1, u + 10, 64);                                                    \
    const float ag1 = __shfl(act1, u + 20, 64);                                                    \
    const float ao1 = __shfl(act1, u + 30, 64);                                                    \
    c1 = fmaf(af1, c1, ai1 * ag1);                                                                 \
    h1n = ao1 * tanh_f(c1);                                                                        \
}while(0)

__global__ __launch_bounds__(64, 1)
void lstm_fused(const float* __restrict__ x,
                const float* __restrict__ conv_w, const float* __restrict__ conv_b,
                const float* __restrict__ w_ih1,  const float* __restrict__ w_hh1,
                const float* __restrict__ b_ih1,  const float* __restrict__ b_hh1,
                const float* __restrict__ w_ih2,  const float* __restrict__ w_hh2,
                const float* __restrict__ b_ih2,  const float* __restrict__ b_hh2,
                const float* __restrict__ lin_w,  const float* __restrict__ lin_b,
                float* __restrict__ out)
{
    __shared__ float wl[64][73];
    const int lane  = threadIdx.x;
    const int batch = blockIdx.x;
    const int grow  = (lane < G4) ? lane : (G4-1);
    const int q     = grow / 10;
    const int u     = grow - q * 10;
    const int ch    = lane & 15;
    const bool isG  = (q == 2);
    float zM = isG ? 2.f : 1.f;
    float aA = isG ? 2.f : 1.f;
    float aB = isG ? -1.f : 0.f;
    PIN(zM); PIN(aA); PIN(aB);

    {
        float* mr_ = wl[lane];
        const float* cwp = conv_w + ch*24;
        #pragma unroll
        for (int m = 0; m < 24; ++m) mr_[m] = cwp[m];
        const float* wip = w_ih1 + grow*CC;
        #pragma unroll
        for (int m = 0; m < CC; ++m) mr_[24+m] = wip[m];
        const float* q1 = w_hh1 + grow*HH;
        const float* q2 = w_ih2 + grow*HH;
        const float* q3 = w_hh2 + grow*HH;
        #pragma unroll
        for (int m = 0; m < HH; ++m){ mr_[40+m]=q1[m]; mr_[50+m]=q2[m]; mr_[60+m]=q3[m]; }
        mr_[70] = b_ih1[grow] + b_hh1[grow];
        mr_[71] = b_ih2[grow] + b_hh2[grow];
        mr_[72] = conv_b[ch];
    }
    __syncthreads();
    const float* mr = wl[lane];

    float cw0=mr[0],  cw1=mr[1],  cw2=mr[2],  cw3=mr[3],  cw4=mr[4],  cw5=mr[5];
    float cw6=mr[6],  cw7=mr[7],  cw8=mr[8],  cw9=mr[9],  cw10=mr[10],cw11=mr[11];
    float cw12=mr[12],cw13=mr[13],cw14=mr[14],cw15=mr[15],cw16=mr[16],cw17=mr[17];
    float cw18=mr[18],cw19=mr[19],cw20=mr[20],cw21=mr[21],cw22=mr[22],cw23=mr[23];
    float wi0=mr[24], wi1=mr[25], wi2=mr[26], wi3=mr[27];
    float wi4=mr[28], wi5=mr[29], wi6=mr[30], wi7=mr[31];
    float wi8=mr[32], wi9=mr[33], wi10=mr[34],wi11=mr[35];
    float wi12=mr[36],wi13=mr[37],wi14=mr[38],wi15=mr[39];
    float wh1_0=mr[40],wh1_1=mr[41],wh1_2=mr[42],wh1_3=mr[43],wh1_4=mr[44];
    float wh1_5=mr[45],wh1_6=mr[46],wh1_7=mr[47],wh1_8=mr[48],wh1_9=mr[49];
    float wi2_0=mr[50],wi2_1=mr[51],wi2_2=mr[52],wi2_3=mr[53],wi2_4=mr[54];
    float wi2_5=mr[55],wi2_6=mr[56],wi2_7=mr[57],wi2_8=mr[58],wi2_9=mr[59];
    float wh2_0=mr[60],wh2_1=mr[61],wh2_2=mr[62],wh2_3=mr[63],wh2_4=mr[64];
    float wh2_5=mr[65],wh2_6=mr[66],wh2_7=mr[67],wh2_8=mr[68],wh2_9=mr[69];
    float b1 = mr[70], b2 = mr[71], cb = mr[72];

    const float* xb = x + (size_t)batch * (TT*FF);
    float h1 = 0.f, c1 = 0.f, h2 = 0.f, c2 = 0.f, h1n;

    float4 w0a = make_float4(0.f,0.f,0.f,0.f), w0b = w0a;
    float4 w1a = *(const float4*)(xb + 0);
    float4 w1b = *(const float4*)(xb + 4);
    float4 w2a = *(const float4*)(xb + 8);
    float4 w2b = *(const float4*)(xb + 12);

    {
        float y0; CONV_Y(y0);
        H1BCAST;
        LAYER1(y0);
        h1 = h1n;
    }
    w0a = w1a; w0b = w1b; w1a = w2a; w1b = w2b;
    w2a = *(const float4*)(xb + 16);
    w2b = *(const float4*)(xb + 20);

    #pragma unroll 3
    for (int t = 1; t < TT; ++t){
        float4 nxa = make_float4(0.f,0.f,0.f,0.f), nxb = nxa;
        if (t + 2 < TT){
            const float* p = xb + (t+2)*FF;
            nxa = *(const float4*)p;
            nxb = *(const float4*)(p + 4);
        }
        float y; CONV_Y(y);
        {
            H1BCAST;
            LAYER2;
            LAYER1(y);
        }
        h1 = h1n;
        w0a = w1a; w0b = w1b; w1a = w2a; w1b = w2b; w2a = nxa; w2b = nxb;
    }
    { H1BCAST; LAYER2; }

    float part = (lane < HH) ? h2 * lin_w[grow] : 0.f;
    #pragma unroll
    for (int off = 8; off > 0; off >>= 1) part += __shfl_xor(part, off, 16);
    if (lane == 0) out[batch] = sigf(part + lin_b[0]);
}

extern "C" void kernel_launch(void* const* d_in, const int* in_sizes, int n_in,
                              void* d_out, int out_size, void* d_ws, size_t ws_size,
                              hipStream_t stream) {
    const float* x      = (const float*)d_in[0];
    const float* conv_w = (const float*)d_in[1];
    const float* conv_b = (const float*)d_in[2];
    const float* w_ih1  = (const float*)d_in[3];
    const float* w_hh1  = (const float*)d_in[4];
    const float* b_ih1  = (const float*)d_in[5];
    const float* b_hh1  = (const float*)d_in[6];
    const float* w_ih2  = (const float*)d_in[7];
    const float* w_hh2  = (const float*)d_in[8];
    const float* b_ih2  = (const float*)d_in[9];
    const float* b_hh2  = (const float*)d_in[10];
    const float* lin_w  = (const float*)d_in[11];
    const float* lin_b  = (const float*)d_in[12];
    float* out = (float*)d_out;

    const int NB = 2048;
    const size_t XG_BYTES = (size_t)NB * TT * G4 * sizeof(float);   // 167,772,160

    if (ws_size >= XG_BYTES){
        float* xgws = (float*)d_ws;
        conv_xg<<<dim3(NB), dim3(64), 0, stream>>>(
            x, conv_w, conv_b, w_ih1, b_ih1, b_hh1, xgws);
        lstm_seq<<<dim3(NB), dim3(64), 0, stream>>>(
            xgws, w_hh1, w_ih2, w_hh2, b_ih2, b_hh2, lin_w, lin_b, out);
    } else {
        lstm_fused<<<dim3(NB), dim3(64), 0, stream>>>(
            x, conv_w, conv_b, w_ih1, w_hh1, b_ih1, b_hh1,
            w_ih2, w_hh2, b_ih2, b_hh2, lin_w, lin_b, out);
    }
}